// Round 14
// baseline (157.249 us; speedup 1.0000x reference)
//
#include <hip/hip_runtime.h>
#include <math.h>

#define DD 128
#define NSRC 8
#define EMAX 32          // 32*64 = 2048 >= (m+1)(m+2)/2  ->  m <= 62 fast path
#define MFAST 62
#define LOG_2PI 1.83787706640934548356f
#define LN2F 0.69314718055994531f
#define EPSF 1e-6f

// wave-local "barrier": compiler fence only (same-wave DS ops are in-order;
// no s_barrier emitted -> the two waves of the WG stay fully independent)
#define WSYNC() do { asm volatile("" ::: "memory"); \
                     __builtin_amdgcn_wave_barrier(); } while (0)

// e -> row index within a packed lower triangle (row r has r+1 elements).
__device__ inline int tri_row_of(int e) {
    float f = sqrtf(8.f * (float)e + 1.f);
    int r = (int)((f - 1.f) * 0.5f);
    if ((r + 1) * (r + 2) / 2 <= e) ++r;
    else if (r * (r + 1) / 2 > e) --r;
    return r;
}

// ---------------------------------------------------------------------------
// K1: fused  (a) miss_mask layout detect -> flagarr[block]  (b) Q_s
//            (c) ldS[s]  (d) block 0 zeroes partial/ovf_cnt      (verified)
// ---------------------------------------------------------------------------
__global__ __launch_bounds__(128) void k_precompute(
    const float* __restrict__ W, const float* __restrict__ ls2,
    const unsigned int* __restrict__ mw, int n_words,
    float* __restrict__ Q, float* __restrict__ ldS,
    int* __restrict__ flagarr, float* __restrict__ partial,
    int* __restrict__ ovf_cnt)
{
    __shared__ float Bs[DD][DD + 1];
    __shared__ float r[4][DD + 1];
    __shared__ float sinv[DD];
    __shared__ float part2[2];
    __shared__ int fsh[2];
    const int tid = threadIdx.x;
    const int s   = blockIdx.x >> 5;
    const int i0  = (blockIdx.x & 31) * 4;

    if (blockIdx.x == 0) {
        if (tid < 64)  partial[tid] = 0.f;
        if (tid == 64) *ovf_cnt = 0;
    }

    int gid = (blockIdx.x * 128 + tid) * 4;
    int f = 0;
    #pragma unroll
    for (int t = 0; t < 4; ++t) {
        int idx = gid + t;
        if (idx < n_words) {
            unsigned int v = mw[idx];
            if (v > 1u) f |= 1;
            if (v == 0x3F800000u) f |= 2;
        }
    }
    unsigned long long bA = __ballot(f & 1);
    unsigned long long bB = __ballot(f & 2);
    if ((tid & 63) == 0) fsh[tid >> 6] = (bA ? 1 : 0) | (bB ? 2 : 0);

    for (int idx = tid; idx < DD * DD; idx += 128) {
        int row = idx >> 7, col = idx & 127;
        Bs[row][col] = (row == col ? 1.f : 0.f) - W[idx];
    }
    sinv[tid] = 1.f / fmaxf(expf(ls2[s * DD + tid]), EPSF);
    __syncthreads();
    if (tid == 0) flagarr[blockIdx.x] = fsh[0] | fsh[1];
    for (int a = 0; a < 4; ++a)
        r[a][tid] = Bs[i0 + a][tid] * sinv[tid];
    __syncthreads();

    const int j = tid;
    float acc0 = 0.f, acc1 = 0.f, acc2 = 0.f, acc3 = 0.f;
    #pragma unroll 4
    for (int d = 0; d < DD; ++d) {
        float bj = Bs[j][d];
        acc0 += r[0][d] * bj;
        acc1 += r[1][d] * bj;
        acc2 += r[2][d] * bj;
        acc3 += r[3][d] * bj;
    }
    size_t base = ((size_t)s * DD + i0) * DD + j;
    Q[base         ] = acc0;
    Q[base +     DD] = acc1;
    Q[base + 2 * DD] = acc2;
    Q[base + 3 * DD] = acc3;

    if (i0 == 0) {
        float v = logf(fmaxf(expf(ls2[s * DD + tid]), EPSF));
        for (int o = 32; o; o >>= 1) v += __shfl_down(v, o, 64);
        if ((tid & 63) == 0) part2[tid >> 6] = v;
        __syncthreads();
        if (tid == 0) ldS[s] = part2[0] + part2[1];
    }
}

// ---------------------------------------------------------------------------
// K2 fast: 128-thread WG = TWO INDEPENDENT WAVES, one sample each, private
// LDS slices, ZERO barriers (wave-local sync only). Body = R13-verified:
// branchless coalesced matvec, direct register-slot fill from L2-resident Q,
// register-resident bordered Cholesky.
// ---------------------------------------------------------------------------
__global__ __launch_bounds__(128) void k_fast(
    const float* __restrict__ data, const float* __restrict__ mu,
    const float* __restrict__ wgt, const int* __restrict__ src,
    const void* __restrict__ miss, const int* __restrict__ flagarr,
    const float* __restrict__ Q, const float* __restrict__ ldS,
    float* __restrict__ partial, int* __restrict__ ovf_cnt,
    int* __restrict__ ovf_list)
{
    __shared__ float xsh[2][DD];
    __shared__ float ysh[2][DD];
    __shared__ int   midx[2][64];
    __shared__ float csc[2][2][64];

    const int w    = threadIdx.x >> 6;
    const int lane = threadIdx.x & 63;
    const int i    = blockIdx.x * 2 + w;
    const int s    = src[i];
    const float* Qs = Q + (size_t)s * DD * DD;
    const size_t base = (size_t)i * DD;
    const int j0 = 2 * lane, j1 = 2 * lane + 1;

    // ---- layout flag: OR-reduce flagarr[256] (written by prior dispatch) ----
    int fl = 0;
    #pragma unroll
    for (int t = 0; t < 4; ++t) fl |= flagarr[lane + 64 * t];
    unsigned long long fb1 = __ballot(fl & 1);
    unsigned long long fb2 = __ballot(fl & 2);
    const int f = (fb1 ? 1 : 0) | (fb2 ? 2 : 0);

    // ---- mask decode (uniform branch on detected layout) ----
    bool mmE, mmO;
    if (f & 2) {
        const float* M = (const float*)miss;
        mmE = M[base + j0] != 0.f;  mmO = M[base + j1] != 0.f;
    } else if (f & 1) {
        const unsigned char* M = (const unsigned char*)miss;
        mmE = M[base + j0] != 0;    mmO = M[base + j1] != 0;
    } else {
        const int* M = (const int*)miss;
        mmE = M[base + j0] != 0;    mmO = M[base + j1] != 0;
    }

    unsigned long long bE = __ballot(mmE), bO = __ballot(mmO);
    const int m = __popcll(bE) + __popcll(bO);
    if (m > MFAST) {   // no barriers in this kernel -> divergent return is safe
        if (lane == 0) { int pos = atomicAdd(ovf_cnt, 1); ovf_list[pos] = i; }
        return;
    }
    unsigned long long lt = (1ull << lane) - 1ull;
    if (mmE) midx[w][__popcll(bE & lt)] = j0;
    if (mmO) midx[w][__popcll(bE) + __popcll(bO & lt)] = j1;

    float x0 = mmE ? 0.f : (data[base + j0] - mu[j0]);
    float x1 = mmO ? 0.f : (data[base + j1] - mu[j1]);
    xsh[w][j0] = x0;
    xsh[w][j1] = x1;
    WSYNC();

    // ---- y = Qx by columns: BRANCHLESS pipelined float2 reads (verified) ----
    float y0 = 0.f, y1 = 0.f, z0 = 0.f, z1 = 0.f;
    #pragma unroll 8
    for (int k = 0; k < DD; k += 2) {
        float xk0 = xsh[w][k], xk1 = xsh[w][k + 1];
        float2 qa = *(const float2*)(Qs + (size_t)k * DD + j0);
        float2 qb = *(const float2*)(Qs + (size_t)(k + 1) * DD + j0);
        y0 += xk0 * qa.x;  y1 += xk0 * qa.y;
        z0 += xk1 * qb.x;  z1 += xk1 * qb.y;
    }
    y0 += z0;  y1 += z1;
    ysh[w][j0] = y0;
    ysh[w][j1] = y1;
    float p = x0 * y0 + x1 * y1;
    for (int o = 32; o; o >>= 1) p += __shfl_down(p, o, 64);   // lane0: x^T Q x
    WSYNC();   // ysh, midx ready (same-wave DS in-order)

    // ---- fill register slots DIRECTLY from Q (independent pipelined loads;
    //      column-major from rightmost column) ----
    const int cntT = ((m + 1) * (m + 2)) >> 1;
    unsigned key[EMAX];
    float    val[EMAX];
    #pragma unroll
    for (int t = 0; t < EMAX; ++t) {
        key[t] = 0u; val[t] = 0.f;
        int e = lane + (t << 6);
        if (e < cntT) {
            int q  = tri_row_of(e);            // q = m - col
            int jc = m - q;                    // column
            int ir = jc + (e - ((q * (q + 1)) >> 1));   // row, jc..m
            float v;
            if (ir == m) {
                v = (jc == m) ? 0.f : ysh[w][midx[w][jc]];  // border row = u
            } else {
                v = Qs[(size_t)(midx[w][ir] * DD + midx[w][jc])];
            }
            key[t] = ((unsigned)jc << 8) | (unsigned)ir;
            val[t] = v;
            if (jc == 0) csc[w][0][ir] = v;    // column 0 seeds buffer A
        }
    }
    WSYNC();

    // ---- wave-synchronous factorization: zero barriers ----
    float logacc = 0.f;
    #pragma unroll 1
    for (int k = 0; k < m; ++k) {
        const int pb = k & 1;
        float dk = csc[w][pb][k];
        float invd = __builtin_amdgcn_rcpf(dk);
        logacc += __log2f(dk);
        const unsigned boundA = (unsigned)(k + 1) << 8;   // alive: key >= boundA
        const unsigned boundB = (unsigned)(k + 2) << 8;   // write: key <  boundB
        #pragma unroll
        for (int t = 0; t < EMAX; ++t) {
            bool alive = (key[t] >= boundA);
            if (!__any(alive)) break;
            if (alive) {
                int ir = (int)(key[t] & 255u);
                int jc = (int)(key[t] >> 8);
                float ci = csc[w][pb][ir];
                float cj = csc[w][pb][jc];
                val[t] -= ci * cj * invd;
                if (key[t] < boundB) csc[w][pb ^ 1][ir] = val[t];
            }
        }
        WSYNC();
    }

    if (lane == 0) {
        // val[0] = element (m,m) = -u^T Qmm^{-1} u ; quad = p + val[0]
        float ll = -0.5f * ((p + val[0]) + logacc * LN2F + ldS[s]
                            + (float)(DD - m) * LOG_2PI);
        atomicAdd(&partial[i & 63], ll * wgt[i]);
    }
}

// ---------------------------------------------------------------------------
// K tail: single block. (a) drain overflow list (m > MFAST; ~always empty)
// with the verified LDS-triangle Cholesky, (b) reduce partial -> out.
// ---------------------------------------------------------------------------
__global__ __launch_bounds__(128) void k_tail(
    const float* __restrict__ data, const float* __restrict__ mu,
    const float* __restrict__ wgt, const int* __restrict__ src,
    const void* __restrict__ miss, const int* __restrict__ flagarr,
    const float* __restrict__ Q, const float* __restrict__ ldS,
    float* __restrict__ partial, const int* __restrict__ ovf_cnt,
    const int* __restrict__ ovf_list, float* __restrict__ out)
{
    __shared__ __align__(16) float xsh[DD];
    __shared__ float ysh[DD];
    __shared__ int   midx[DD];
    __shared__ float cscv[DD + 1];
    __shared__ float tri[(DD + 1) * (DD + 2) / 2];
    __shared__ float bc[2];
    __shared__ float red[2];
    __shared__ int   sh_m;
    __shared__ int   sh_f;

    const int tid = threadIdx.x;
    if (tid == 0) sh_f = 0;
    __syncthreads();
    {
        int fl = flagarr[tid] | flagarr[tid + 128];
        if (fl) atomicOr(&sh_f, fl);
    }
    __syncthreads();
    const int f = sh_f;

    const int novf = *ovf_cnt;
    for (int j = 0; j < novf; ++j) {
        const int i = ovf_list[j];
        if (tid == 0) sh_m = 0;
        __syncthreads();

        const int s = src[i];
        const float* Qs = Q + (size_t)s * DD * DD;
        const size_t g = (size_t)i * DD + tid;
        bool mm;
        if (f & 2)      mm = ((const float*)miss)[g] != 0.f;
        else if (f & 1) mm = ((const unsigned char*)miss)[g] != 0;
        else            mm = ((const int*)miss)[g] != 0;

        float xv = mm ? 0.f : (data[g] - mu[tid]);
        xsh[tid] = xv;
        if (mm) { int pos = atomicAdd(&sh_m, 1); midx[pos] = tid; }
        __syncthreads();
        const int m = sh_m;

        const float4* qrow = (const float4*)(Qs + (size_t)tid * DD);
        const float4* x4   = (const float4*)xsh;
        float acc = 0.f;
        #pragma unroll 8
        for (int d = 0; d < DD / 4; ++d) {
            float4 q = qrow[d], xx = x4[d];
            acc += q.x * xx.x + q.y * xx.y + q.z * xx.z + q.w * xx.w;
        }
        ysh[tid] = acc;
        float pp = xv * acc;
        for (int o = 32; o; o >>= 1) pp += __shfl_down(pp, o, 64);
        if ((tid & 63) == 0) red[tid >> 6] = pp;
        __syncthreads();

        const int cntA = (m * (m + 1)) >> 1;
        for (int e = tid; e < cntA; e += 128) {
            int a = tri_row_of(e);
            int b = e - ((a * (a + 1)) >> 1);
            tri[e] = Qs[(size_t)midx[a] * DD + midx[b]];
        }
        for (int b = tid; b < m; b += 128) tri[cntA + b] = ysh[midx[b]];
        if (tid == 0) tri[cntA + m] = 0.f;
        __syncthreads();

        float logacc = 0.f;
        if (m > 0) {
            if (tid == 0) {
                float d0 = tri[0];
                bc[1] = d0;
                float sq = sqrtf(d0);
                bc[0] = 1.f / sq;
                tri[0] = sq;
            }
            __syncthreads();
            for (int k = 0; k < m; ++k) {
                float inv = bc[0];
                if (tid == 0) logacc += logf(bc[1]);
                for (int ii = k + 1 + tid; ii <= m; ii += 128) {
                    int off = (ii * (ii + 1)) >> 1;
                    float v = tri[off + k] * inv;
                    tri[off + k] = v;
                    cscv[ii] = v;
                }
                __syncthreads();
                int qn  = m - k;
                int cnt = (qn * (qn + 1)) >> 1;
                for (int e = tid; e < cnt; e += 128) {
                    int ri = tri_row_of(e);
                    int rj = e - ((ri * (ri + 1)) >> 1);
                    int ii = k + 1 + ri, jj = k + 1 + rj;
                    int off = (ii * (ii + 1)) >> 1;
                    float v = tri[off + jj] - cscv[ii] * cscv[jj];
                    if (ii == jj && jj == k + 1 && k + 1 < m) {
                        bc[1] = v;
                        float sq = sqrtf(v);
                        bc[0] = 1.f / sq;
                        tri[off + jj] = sq;
                    } else {
                        tri[off + jj] = v;
                    }
                }
                __syncthreads();
            }
        }

        if (tid == 0) {
            float quad2 = (m > 0) ? -tri[cntA + m] : 0.f;
            float quad1 = red[0] + red[1];
            float ll = -0.5f * ((quad1 - quad2) + logacc + ldS[s]
                                + (float)(DD - m) * LOG_2PI);
            atomicAdd(&partial[i & 63], ll * wgt[i]);
        }
        __syncthreads();
    }

    __syncthreads();
    if (tid < 64) {
        float v = partial[tid];
        for (int o = 32; o; o >>= 1) v += __shfl_down(v, o, 64);
        if (tid == 0) out[0] = v;
    }
}

// ---------------------------------------------------------------------------
extern "C" void kernel_launch(void* const* d_in, const int* in_sizes, int n_in,
                              void* d_out, int out_size, void* d_ws, size_t ws_size,
                              hipStream_t stream)
{
    const float* data = (const float*)d_in[0];
    const float* W    = (const float*)d_in[1];
    const float* ls2  = (const float*)d_in[2];
    const float* mu   = (const float*)d_in[3];
    const float* wgt  = (const float*)d_in[4];
    const int*   src  = (const int*)d_in[5];
    const void*  miss = (const void*)d_in[6];
    float* out = (float*)d_out;

    float* Q        = (float*)d_ws;                    // 131072 floats
    float* ldS      = Q + (size_t)NSRC * DD * DD;      // 8
    float* partial  = ldS + NSRC;                      // 64
    int*   flagarr  = (int*)(partial + 64);            // 256
    int*   ovf_cnt  = flagarr + 256;                   // 1
    int*   ovf_list = ovf_cnt + 1;                     // 4096

    const int n       = in_sizes[0] / DD;              // 4096 samples
    const int n_words = (n * DD) / 4;                  // 131072

    hipLaunchKernelGGL(k_precompute, dim3(NSRC * 32), dim3(128), 0, stream,
                       W, ls2, (const unsigned int*)miss, n_words,
                       Q, ldS, flagarr, partial, ovf_cnt);
    hipLaunchKernelGGL(k_fast, dim3(n / 2), dim3(128), 0, stream,
                       data, mu, wgt, src, miss, flagarr, Q, ldS,
                       partial, ovf_cnt, ovf_list);
    hipLaunchKernelGGL(k_tail, dim3(1), dim3(128), 0, stream,
                       data, mu, wgt, src, miss, flagarr, Q, ldS,
                       partial, ovf_cnt, ovf_list, out);
}

// Round 15
// 153.689 us; speedup vs baseline: 1.0232x; 1.0232x over previous
//
#include <hip/hip_runtime.h>
#include <math.h>

#define DD 128
#define NSRC 8
#define EMAX 32          // 32*64 = 2048 >= (m+1)(m+2)/2  ->  m <= 62 fast path
#define MFAST 62
#define LOG_2PI 1.83787706640934548356f
#define LN2F 0.69314718055994531f
#define EPSF 1e-6f

// e -> row index within a packed lower triangle (row r has r+1 elements).
__device__ inline int tri_row_of(int e) {
    float f = sqrtf(8.f * (float)e + 1.f);
    int r = (int)((f - 1.f) * 0.5f);
    if ((r + 1) * (r + 2) / 2 <= e) ++r;
    else if (r * (r + 1) / 2 > e) --r;
    return r;
}

// ---------------------------------------------------------------------------
// K1: fused  (a) miss_mask layout detect -> flagarr[block]  (b) Q_s
//            (c) ldS[s]  (d) block 0 zeroes partial/ovf_cnt      (verified)
// ---------------------------------------------------------------------------
__global__ __launch_bounds__(128) void k_precompute(
    const float* __restrict__ W, const float* __restrict__ ls2,
    const unsigned int* __restrict__ mw, int n_words,
    float* __restrict__ Q, float* __restrict__ ldS,
    int* __restrict__ flagarr, float* __restrict__ partial,
    int* __restrict__ ovf_cnt)
{
    __shared__ float Bs[DD][DD + 1];
    __shared__ float r[4][DD + 1];
    __shared__ float sinv[DD];
    __shared__ float part2[2];
    __shared__ int fsh[2];
    const int tid = threadIdx.x;
    const int s   = blockIdx.x >> 5;
    const int i0  = (blockIdx.x & 31) * 4;

    if (blockIdx.x == 0) {
        if (tid < 64)  partial[tid] = 0.f;
        if (tid == 64) *ovf_cnt = 0;
    }

    int gid = (blockIdx.x * 128 + tid) * 4;
    int f = 0;
    #pragma unroll
    for (int t = 0; t < 4; ++t) {
        int idx = gid + t;
        if (idx < n_words) {
            unsigned int v = mw[idx];
            if (v > 1u) f |= 1;
            if (v == 0x3F800000u) f |= 2;
        }
    }
    unsigned long long bA = __ballot(f & 1);
    unsigned long long bB = __ballot(f & 2);
    if ((tid & 63) == 0) fsh[tid >> 6] = (bA ? 1 : 0) | (bB ? 2 : 0);

    for (int idx = tid; idx < DD * DD; idx += 128) {
        int row = idx >> 7, col = idx & 127;
        Bs[row][col] = (row == col ? 1.f : 0.f) - W[idx];
    }
    sinv[tid] = 1.f / fmaxf(expf(ls2[s * DD + tid]), EPSF);
    __syncthreads();
    if (tid == 0) flagarr[blockIdx.x] = fsh[0] | fsh[1];
    for (int a = 0; a < 4; ++a)
        r[a][tid] = Bs[i0 + a][tid] * sinv[tid];
    __syncthreads();

    const int j = tid;
    float acc0 = 0.f, acc1 = 0.f, acc2 = 0.f, acc3 = 0.f;
    #pragma unroll 4
    for (int d = 0; d < DD; ++d) {
        float bj = Bs[j][d];
        acc0 += r[0][d] * bj;
        acc1 += r[1][d] * bj;
        acc2 += r[2][d] * bj;
        acc3 += r[3][d] * bj;
    }
    size_t base = ((size_t)s * DD + i0) * DD + j;
    Q[base         ] = acc0;
    Q[base +     DD] = acc1;
    Q[base + 2 * DD] = acc2;
    Q[base + 3 * DD] = acc3;

    if (i0 == 0) {
        float v = logf(fmaxf(expf(ls2[s * DD + tid]), EPSF));
        for (int o = 32; o; o >>= 1) v += __shfl_down(v, o, 64);
        if ((tid & 63) == 0) part2[tid >> 6] = v;
        __syncthreads();
        if (tid == 0) ldS[s] = part2[0] + part2[1];
    }
}

// ---------------------------------------------------------------------------
// K2 fast: ONE WAVE per sample (R13-verified best):
//  - y = Qx by columns, branchless pipelined float2 reads
//  - register slots filled directly from L2-resident Q (1.8 KB LDS total)
//  - register-resident bordered Cholesky, one barrier per step
// ---------------------------------------------------------------------------
__global__ __launch_bounds__(64) void k_fast(
    const float* __restrict__ data, const float* __restrict__ mu,
    const float* __restrict__ wgt, const int* __restrict__ src,
    const void* __restrict__ miss, const int* __restrict__ flagarr,
    const float* __restrict__ Q, const float* __restrict__ ldS,
    float* __restrict__ partial, int* __restrict__ ovf_cnt,
    int* __restrict__ ovf_list)
{
    __shared__ float xsh[DD];
    __shared__ float ysh[DD];
    __shared__ int   midx[64];
    __shared__ float csc[2][64];

    const int i = blockIdx.x, lane = threadIdx.x;
    const int s = src[i];
    const float* Qs = Q + (size_t)s * DD * DD;
    const size_t base = (size_t)i * DD;
    const int j0 = 2 * lane, j1 = 2 * lane + 1;

    // ---- layout flag: OR-reduce flagarr[256] (written by prior dispatch) ----
    int fl = 0;
    #pragma unroll
    for (int t = 0; t < 4; ++t) fl |= flagarr[lane + 64 * t];
    unsigned long long fb1 = __ballot(fl & 1);
    unsigned long long fb2 = __ballot(fl & 2);
    const int f = (fb1 ? 1 : 0) | (fb2 ? 2 : 0);

    // ---- mask decode (uniform branch on detected layout) ----
    bool mmE, mmO;
    if (f & 2) {
        const float* M = (const float*)miss;
        mmE = M[base + j0] != 0.f;  mmO = M[base + j1] != 0.f;
    } else if (f & 1) {
        const unsigned char* M = (const unsigned char*)miss;
        mmE = M[base + j0] != 0;    mmO = M[base + j1] != 0;
    } else {
        const int* M = (const int*)miss;
        mmE = M[base + j0] != 0;    mmO = M[base + j1] != 0;
    }

    unsigned long long bE = __ballot(mmE), bO = __ballot(mmO);
    const int m = __popcll(bE) + __popcll(bO);
    if (m > MFAST) {
        if (lane == 0) { int pos = atomicAdd(ovf_cnt, 1); ovf_list[pos] = i; }
        return;
    }
    unsigned long long lt = (1ull << lane) - 1ull;
    if (mmE) midx[__popcll(bE & lt)] = j0;
    if (mmO) midx[__popcll(bE) + __popcll(bO & lt)] = j1;

    float x0 = mmE ? 0.f : (data[base + j0] - mu[j0]);
    float x1 = mmO ? 0.f : (data[base + j1] - mu[j1]);
    xsh[j0] = x0;
    xsh[j1] = x1;
    __syncthreads();

    // ---- y = Qx by columns: BRANCHLESS pipelined float2 reads (verified) ----
    float y0 = 0.f, y1 = 0.f, z0 = 0.f, z1 = 0.f;
    #pragma unroll 8
    for (int k = 0; k < DD; k += 2) {
        float xk0 = xsh[k], xk1 = xsh[k + 1];
        float2 qa = *(const float2*)(Qs + (size_t)k * DD + j0);
        float2 qb = *(const float2*)(Qs + (size_t)(k + 1) * DD + j0);
        y0 += xk0 * qa.x;  y1 += xk0 * qa.y;
        z0 += xk1 * qb.x;  z1 += xk1 * qb.y;
    }
    y0 += z0;  y1 += z1;
    ysh[j0] = y0;
    ysh[j1] = y1;
    float p = x0 * y0 + x1 * y1;
    for (int o = 32; o; o >>= 1) p += __shfl_down(p, o, 64);   // lane0: x^T Q x
    __syncthreads();   // ysh, midx ready

    // ---- fill register slots DIRECTLY from Q (independent pipelined loads,
    //      column-major from rightmost column) ----
    const int cntT = ((m + 1) * (m + 2)) >> 1;
    unsigned key[EMAX];
    float    val[EMAX];
    #pragma unroll
    for (int t = 0; t < EMAX; ++t) {
        key[t] = 0u; val[t] = 0.f;
        int e = lane + (t << 6);
        if (e < cntT) {
            int q  = tri_row_of(e);            // q = m - col
            int jc = m - q;                    // column
            int ir = jc + (e - ((q * (q + 1)) >> 1));   // row, jc..m
            float v;
            if (ir == m) {
                v = (jc == m) ? 0.f : ysh[midx[jc]];    // border row = u
            } else {
                v = Qs[(size_t)(midx[ir] * DD + midx[jc])];
            }
            key[t] = ((unsigned)jc << 8) | (unsigned)ir;
            val[t] = v;
            if (jc == 0) csc[0][ir] = v;       // column 0 seeds buffer A
        }
    }
    __syncthreads();

    // ---- wave-synchronous factorization: one barrier per step ----
    float logacc = 0.f;
    #pragma unroll 1
    for (int k = 0; k < m; ++k) {
        const int pb = k & 1;
        float dk = csc[pb][k];
        float invd = __builtin_amdgcn_rcpf(dk);
        logacc += __log2f(dk);
        const unsigned boundA = (unsigned)(k + 1) << 8;   // alive: key >= boundA
        const unsigned boundB = (unsigned)(k + 2) << 8;   // write: key <  boundB
        #pragma unroll
        for (int t = 0; t < EMAX; ++t) {
            bool alive = (key[t] >= boundA);
            if (!__any(alive)) break;
            if (alive) {
                int ir = (int)(key[t] & 255u);
                int jc = (int)(key[t] >> 8);
                float ci = csc[pb][ir];
                float cj = csc[pb][jc];
                val[t] -= ci * cj * invd;
                if (key[t] < boundB) csc[pb ^ 1][ir] = val[t];
            }
        }
        __syncthreads();
    }

    if (lane == 0) {
        // val[0] = element (m,m) = -u^T Qmm^{-1} u ; quad = p + val[0]
        float ll = -0.5f * ((p + val[0]) + logacc * LN2F + ldS[s]
                            + (float)(DD - m) * LOG_2PI);
        atomicAdd(&partial[i & 63], ll * wgt[i]);
    }
}

// ---------------------------------------------------------------------------
// K tail: single block. (a) drain overflow list (m > MFAST; ~always empty)
// with the verified LDS-triangle Cholesky, (b) reduce partial -> out.
// ---------------------------------------------------------------------------
__global__ __launch_bounds__(128) void k_tail(
    const float* __restrict__ data, const float* __restrict__ mu,
    const float* __restrict__ wgt, const int* __restrict__ src,
    const void* __restrict__ miss, const int* __restrict__ flagarr,
    const float* __restrict__ Q, const float* __restrict__ ldS,
    float* __restrict__ partial, const int* __restrict__ ovf_cnt,
    const int* __restrict__ ovf_list, float* __restrict__ out)
{
    __shared__ __align__(16) float xsh[DD];
    __shared__ float ysh[DD];
    __shared__ int   midx[DD];
    __shared__ float cscv[DD + 1];
    __shared__ float tri[(DD + 1) * (DD + 2) / 2];
    __shared__ float bc[2];
    __shared__ float red[2];
    __shared__ int   sh_m;
    __shared__ int   sh_f;

    const int tid = threadIdx.x;
    if (tid == 0) sh_f = 0;
    __syncthreads();
    {
        int fl = flagarr[tid] | flagarr[tid + 128];
        if (fl) atomicOr(&sh_f, fl);
    }
    __syncthreads();
    const int f = sh_f;

    const int novf = *ovf_cnt;
    for (int j = 0; j < novf; ++j) {
        const int i = ovf_list[j];
        if (tid == 0) sh_m = 0;
        __syncthreads();

        const int s = src[i];
        const float* Qs = Q + (size_t)s * DD * DD;
        const size_t g = (size_t)i * DD + tid;
        bool mm;
        if (f & 2)      mm = ((const float*)miss)[g] != 0.f;
        else if (f & 1) mm = ((const unsigned char*)miss)[g] != 0;
        else            mm = ((const int*)miss)[g] != 0;

        float xv = mm ? 0.f : (data[g] - mu[tid]);
        xsh[tid] = xv;
        if (mm) { int pos = atomicAdd(&sh_m, 1); midx[pos] = tid; }
        __syncthreads();
        const int m = sh_m;

        const float4* qrow = (const float4*)(Qs + (size_t)tid * DD);
        const float4* x4   = (const float4*)xsh;
        float acc = 0.f;
        #pragma unroll 8
        for (int d = 0; d < DD / 4; ++d) {
            float4 q = qrow[d], xx = x4[d];
            acc += q.x * xx.x + q.y * xx.y + q.z * xx.z + q.w * xx.w;
        }
        ysh[tid] = acc;
        float pp = xv * acc;
        for (int o = 32; o; o >>= 1) pp += __shfl_down(pp, o, 64);
        if ((tid & 63) == 0) red[tid >> 6] = pp;
        __syncthreads();

        const int cntA = (m * (m + 1)) >> 1;
        for (int e = tid; e < cntA; e += 128) {
            int a = tri_row_of(e);
            int b = e - ((a * (a + 1)) >> 1);
            tri[e] = Qs[(size_t)midx[a] * DD + midx[b]];
        }
        for (int b = tid; b < m; b += 128) tri[cntA + b] = ysh[midx[b]];
        if (tid == 0) tri[cntA + m] = 0.f;
        __syncthreads();

        float logacc = 0.f;
        if (m > 0) {
            if (tid == 0) {
                float d0 = tri[0];
                bc[1] = d0;
                float sq = sqrtf(d0);
                bc[0] = 1.f / sq;
                tri[0] = sq;
            }
            __syncthreads();
            for (int k = 0; k < m; ++k) {
                float inv = bc[0];
                if (tid == 0) logacc += logf(bc[1]);
                for (int ii = k + 1 + tid; ii <= m; ii += 128) {
                    int off = (ii * (ii + 1)) >> 1;
                    float v = tri[off + k] * inv;
                    tri[off + k] = v;
                    cscv[ii] = v;
                }
                __syncthreads();
                int qn  = m - k;
                int cnt = (qn * (qn + 1)) >> 1;
                for (int e = tid; e < cnt; e += 128) {
                    int ri = tri_row_of(e);
                    int rj = e - ((ri * (ri + 1)) >> 1);
                    int ii = k + 1 + ri, jj = k + 1 + rj;
                    int off = (ii * (ii + 1)) >> 1;
                    float v = tri[off + jj] - cscv[ii] * cscv[jj];
                    if (ii == jj && jj == k + 1 && k + 1 < m) {
                        bc[1] = v;
                        float sq = sqrtf(v);
                        bc[0] = 1.f / sq;
                        tri[off + jj] = sq;
                    } else {
                        tri[off + jj] = v;
                    }
                }
                __syncthreads();
            }
        }

        if (tid == 0) {
            float quad2 = (m > 0) ? -tri[cntA + m] : 0.f;
            float quad1 = red[0] + red[1];
            float ll = -0.5f * ((quad1 - quad2) + logacc + ldS[s]
                                + (float)(DD - m) * LOG_2PI);
            atomicAdd(&partial[i & 63], ll * wgt[i]);
        }
        __syncthreads();
    }

    __syncthreads();
    if (tid < 64) {
        float v = partial[tid];
        for (int o = 32; o; o >>= 1) v += __shfl_down(v, o, 64);
        if (tid == 0) out[0] = v;
    }
}

// ---------------------------------------------------------------------------
extern "C" void kernel_launch(void* const* d_in, const int* in_sizes, int n_in,
                              void* d_out, int out_size, void* d_ws, size_t ws_size,
                              hipStream_t stream)
{
    const float* data = (const float*)d_in[0];
    const float* W    = (const float*)d_in[1];
    const float* ls2  = (const float*)d_in[2];
    const float* mu   = (const float*)d_in[3];
    const float* wgt  = (const float*)d_in[4];
    const int*   src  = (const int*)d_in[5];
    const void*  miss = (const void*)d_in[6];
    float* out = (float*)d_out;

    float* Q        = (float*)d_ws;                    // 131072 floats
    float* ldS      = Q + (size_t)NSRC * DD * DD;      // 8
    float* partial  = ldS + NSRC;                      // 64
    int*   flagarr  = (int*)(partial + 64);            // 256
    int*   ovf_cnt  = flagarr + 256;                   // 1
    int*   ovf_list = ovf_cnt + 1;                     // 4096

    const int n       = in_sizes[0] / DD;              // 4096 samples
    const int n_words = (n * DD) / 4;                  // 131072

    hipLaunchKernelGGL(k_precompute, dim3(NSRC * 32), dim3(128), 0, stream,
                       W, ls2, (const unsigned int*)miss, n_words,
                       Q, ldS, flagarr, partial, ovf_cnt);
    hipLaunchKernelGGL(k_fast, dim3(n), dim3(64), 0, stream,
                       data, mu, wgt, src, miss, flagarr, Q, ldS,
                       partial, ovf_cnt, ovf_list);
    hipLaunchKernelGGL(k_tail, dim3(1), dim3(128), 0, stream,
                       data, mu, wgt, src, miss, flagarr, Q, ldS,
                       partial, ovf_cnt, ovf_list, out);
}